// Round 1
// baseline (570.848 us; speedup 1.0000x reference)
//
#include <hip/hip_runtime.h>

#define WS 9
#define WT 1
#define PS 7
#define KMAX 10
#define STRIDE0 4
#define NEPOCHS 100
#define BB 1
#define TT 5
#define CC 3
#define HH 256
#define WW 256
#define NH ((HH - 1) / STRIDE0 + 1)   // 64
#define NW ((WW - 1) / STRIDE0 + 1)   // 64
#define QQ (TT * NH * NW)             // 20480
#define NOFF (3 * WS * WS)            // 243
#define SELF_IDX ((WS / 2) * WS + (WS / 2))  // 40

static __device__ __forceinline__ int k_eff_from_epoch(int ep) {
    int k = (int)((double)KMAX * ((double)(NEPOCHS - ep) / (double)NEPOCHS) * 1.0);
    return k < 2 ? 2 : k;
}

__global__ __launch_bounds__(256) void dnls_query_kernel(
    const float* __restrict__ noisy, const float* __restrict__ deno,
    const float* __restrict__ fflow, const float* __restrict__ bflow,
    const int* __restrict__ ep_ptr, float* __restrict__ partial)
{
    const int q   = blockIdx.x;          // 0 .. B*QQ-1
    const int b   = q / QQ;
    const int qq  = q % QQ;
    const int tqi = qq / (NH * NW);
    const int r   = qq % (NH * NW);
    const int hq  = (r / NW) * STRIDE0;
    const int wq  = (r % NW) * STRIDE0;
    const int tid = threadIdx.x;

    const int k_eff = k_eff_from_epoch(ep_ptr[0]);

    __shared__ float qpat[CC][PS][PS];   // noisy query patch (search stage)
    __shared__ float dpat[CC][PS][PS];   // deno query patch (refine stage)
    __shared__ float dists[NOFF];
    __shared__ int   tcen[3], hcen[3], wcen[3];
    __shared__ int   sel[KMAX];
    __shared__ float red[256];

    // --- centers from rounded flow at the query location ---
    if (tid == 0) {
        const int HW = HH * WW;
        const size_t base_f = ((size_t)(b * TT + tqi) * 2) * HW + (size_t)hq * WW + wq;
        const int ifdx = (int)rintf(fflow[base_f]);
        const int ifdy = (int)rintf(fflow[base_f + HW]);
        const int ibdx = (int)rintf(bflow[base_f]);
        const int ibdy = (int)rintf(bflow[base_f + HW]);
        tcen[0] = tqi;
        tcen[1] = max(tqi - 1, 0);
        tcen[2] = min(tqi + 1, TT - 1);
        hcen[0] = hq;
        hcen[1] = min(max(hq + ibdy, 0), HH - 1);
        hcen[2] = min(max(hq + ifdy, 0), HH - 1);
        wcen[0] = wq;
        wcen[1] = min(max(wq + ibdx, 0), WW - 1);
        wcen[2] = min(max(wq + ifdx, 0), WW - 1);
    }

    // --- stage query patches in LDS ---
    if (tid < CC * PS * PS) {
        const int c = tid / (PS * PS);
        const int ij = tid % (PS * PS);
        const int i = ij / PS, j = ij % PS;
        const int hh = min(hq + i, HH - 1);
        const int ww = min(wq + j, WW - 1);
        const size_t idx = ((size_t)((b * TT + tqi) * CC + c)) * HH * WW + (size_t)hh * WW + ww;
        qpat[c][i][j] = noisy[idx];
        dpat[c][i][j] = deno[idx];
    }
    __syncthreads();

    // --- one thread per offset: L2 distance noisy-query vs noisy-candidate ---
    if (tid < NOFF) {
        const int dti = tid / (WS * WS);
        const int rr  = tid % (WS * WS);
        const int dh  = rr / WS - WS / 2;
        const int dw  = rr % WS - WS / 2;
        const int tc  = tcen[dti];
        const int hc  = min(max(hcen[dti] + dh, 0), HH - 1);
        const int wc  = min(max(wcen[dti] + dw, 0), WW - 1);
        const float* vb = noisy + ((size_t)((b * TT + tc) * CC)) * HH * WW;
        float acc = 0.f;
        for (int c = 0; c < CC; ++c) {
            const float* vc = vb + (size_t)c * HH * WW;
            for (int i = 0; i < PS; ++i) {
                const int hh = min(hc + i, HH - 1);
                const float* row = vc + (size_t)hh * WW;
                for (int j = 0; j < PS; ++j) {
                    const int ww = min(wc + j, WW - 1);
                    const float dlt = qpat[c][i][j] - row[ww];
                    acc += dlt * dlt;
                }
            }
        }
        dists[tid] = acc;
    }
    __syncthreads();
    if (tid == 0) dists[SELF_IDX] = -INFINITY;  // anchor self to slot 0
    __syncthreads();

    // --- wave-0 iterative argmin (k_eff picks, ties -> lowest index) ---
    if (tid < 64) {
        for (int k = 0; k < k_eff; ++k) {
            float bv = INFINITY;
            int   bi = NOFF;
            for (int n = tid; n < NOFF; n += 64) {
                const float v = dists[n];      // ascending scan: strict < keeps lowest idx
                if (v < bv) { bv = v; bi = n; }
            }
            for (int off = 32; off > 0; off >>= 1) {
                const float ov = __shfl_down(bv, off);
                const int   oi = __shfl_down(bi, off);
                if (ov < bv || (ov == bv && oi < bi)) { bv = ov; bi = oi; }
            }
            bi = __shfl(bi, 0);
            if (tid == 0) sel[k] = bi;
            dists[bi] = INFINITY;              // all lanes write same value: benign
        }
    }
    __syncthreads();

    // --- refine: deno-query vs noisy at selected positions (slots 1..k_eff-1) ---
    float part = 0.f;
    const int nref = (k_eff - 1) * PS * PS;
    for (int u = tid; u < nref; u += 256) {
        const int k  = u / (PS * PS) + 1;
        const int ij = u % (PS * PS);
        const int i  = ij / PS, j = ij % PS;
        const int n  = sel[k];
        const int dti = n / (WS * WS);
        const int rr  = n % (WS * WS);
        const int dh  = rr / WS - WS / 2;
        const int dw  = rr % WS - WS / 2;
        const int tc  = tcen[dti];
        const int hc  = min(max(hcen[dti] + dh, 0), HH - 1);
        const int wc  = min(max(wcen[dti] + dw, 0), WW - 1);
        const int hh  = min(hc + i, HH - 1);
        const int ww  = min(wc + j, WW - 1);
        const float* vb = noisy + ((size_t)((b * TT + tc) * CC)) * HH * WW + (size_t)hh * WW + ww;
        for (int c = 0; c < CC; ++c) {
            const float dlt = dpat[c][i][j] - vb[(size_t)c * HH * WW];
            part += dlt * dlt;
        }
    }

    red[tid] = part;
    __syncthreads();
    for (int s = 128; s > 0; s >>= 1) {
        if (tid < s) red[tid] += red[tid + s];
        __syncthreads();
    }
    if (tid == 0) partial[q] = red[0];
}

__global__ __launch_bounds__(1024) void dnls_reduce_kernel(
    const float* __restrict__ partial, int n,
    const int* __restrict__ ep_ptr, float* __restrict__ out)
{
    const int tid = threadIdx.x;
    double acc = 0.0;
    for (int i = tid; i < n; i += 1024) acc += (double)partial[i];
    __shared__ double red[1024];
    red[tid] = acc;
    __syncthreads();
    for (int s = 512; s > 0; s >>= 1) {
        if (tid < s) red[tid] += red[tid + s];
        __syncthreads();
    }
    if (tid == 0) {
        const int k_eff = k_eff_from_epoch(ep_ptr[0]);
        out[0] = (float)(red[0] / ((double)n * (double)(k_eff - 1)));
    }
}

extern "C" void kernel_launch(void* const* d_in, const int* in_sizes, int n_in,
                              void* d_out, int out_size, void* d_ws, size_t ws_size,
                              hipStream_t stream) {
    const float* noisy = (const float*)d_in[0];
    const float* deno  = (const float*)d_in[1];
    const float* fflow = (const float*)d_in[2];
    const float* bflow = (const float*)d_in[3];
    const int*   ep    = (const int*)d_in[4];
    float* partial = (float*)d_ws;            // BB*QQ floats = 80 KB
    float* out = (float*)d_out;

    dnls_query_kernel<<<BB * QQ, 256, 0, stream>>>(noisy, deno, fflow, bflow, ep, partial);
    dnls_reduce_kernel<<<1, 1024, 0, stream>>>(partial, BB * QQ, ep, out);
}

// Round 2
// 351.918 us; speedup vs baseline: 1.6221x; 1.6221x over previous
//
#include <hip/hip_runtime.h>

#define WS 9
#define WT 1
#define PS 7
#define KMAX 10
#define STRIDE0 4
#define NEPOCHS 100
#define BB 1
#define TT 5
#define CC 3
#define HH 256
#define WW 256
#define NH ((HH - 1) / STRIDE0 + 1)   // 64
#define NW ((WW - 1) / STRIDE0 + 1)   // 64
#define QQ (TT * NH * NW)             // 20480
#define NOFF (3 * WS * WS)            // 243
#define SELF_IDX ((WS / 2) * WS + (WS / 2))  // 40
#define TILE (PS + WS - 1)            // 15: union footprint of 9 centers x 7 patch

static __device__ __forceinline__ int k_eff_from_epoch(int ep) {
    int k = (int)((double)KMAX * ((double)(NEPOCHS - ep) / (double)NEPOCHS) * 1.0);
    return k < 2 ? 2 : k;
}

__global__ __launch_bounds__(256) void dnls_query_kernel(
    const float* __restrict__ noisy, const float* __restrict__ deno,
    const float* __restrict__ fflow, const float* __restrict__ bflow,
    const int* __restrict__ ep_ptr, float* __restrict__ partial)
{
    const int q   = blockIdx.x;          // 0 .. B*QQ-1
    const int b   = q / QQ;
    const int qq  = q % QQ;
    const int tqi = qq / (NH * NW);
    const int r   = qq % (NH * NW);
    const int hq  = (r / NW) * STRIDE0;
    const int wq  = (r % NW) * STRIDE0;
    const int tid = threadIdx.x;
    const int HW  = HH * WW;

    const int k_eff = k_eff_from_epoch(ep_ptr[0]);

    __shared__ float tile[3][CC][TILE][TILE]; // union search windows (noisy)
    __shared__ float qpat[CC][PS][PS];        // noisy query patch (search stage)
    __shared__ float dpat[CC][PS][PS];        // deno query patch (refine stage)
    __shared__ float dists[NOFF];
    __shared__ int   tcen[3], hcen[3], wcen[3], h0s[3], w0s[3];
    __shared__ int   sel[KMAX];
    __shared__ float red[256];

    // --- centers from rounded flow at the query location ---
    if (tid == 0) {
        const size_t base_f = ((size_t)(b * TT + tqi) * 2) * HW + (size_t)hq * WW + wq;
        const int ifdx = (int)rintf(fflow[base_f]);
        const int ifdy = (int)rintf(fflow[base_f + HW]);
        const int ibdx = (int)rintf(bflow[base_f]);
        const int ibdy = (int)rintf(bflow[base_f + HW]);
        tcen[0] = tqi;
        tcen[1] = max(tqi - 1, 0);
        tcen[2] = min(tqi + 1, TT - 1);
        hcen[0] = hq;
        hcen[1] = min(max(hq + ibdy, 0), HH - 1);
        hcen[2] = min(max(hq + ifdy, 0), HH - 1);
        wcen[0] = wq;
        wcen[1] = min(max(wq + ibdx, 0), WW - 1);
        wcen[2] = min(max(wq + ifdx, 0), WW - 1);
        #pragma unroll
        for (int d = 0; d < 3; ++d) {
            h0s[d] = max(hcen[d] - WS / 2, 0);
            w0s[d] = max(wcen[d] - WS / 2, 0);
        }
    }
    __syncthreads();

    // --- stage the 3 union windows (2025 floats) into LDS, coalesced ---
    for (int idx = tid; idx < 3 * CC * TILE * TILE; idx += 256) {
        const int dti = idx / (CC * TILE * TILE);
        const int r1  = idx % (CC * TILE * TILE);
        const int c   = r1 / (TILE * TILE);
        const int ij  = r1 % (TILE * TILE);
        const int i   = ij / TILE, j = ij % TILE;
        const int hh  = min(h0s[dti] + i, HH - 1);
        const int ww  = min(w0s[dti] + j, WW - 1);
        tile[dti][c][i][j] =
            noisy[((size_t)((b * TT + tcen[dti]) * CC + c)) * HW + (size_t)hh * WW + ww];
    }
    // --- stage query patches in LDS ---
    if (tid < CC * PS * PS) {
        const int c = tid / (PS * PS);
        const int ij = tid % (PS * PS);
        const int i = ij / PS, j = ij % PS;
        const int hh = min(hq + i, HH - 1);
        const int ww = min(wq + j, WW - 1);
        const size_t idx = ((size_t)((b * TT + tqi) * CC + c)) * HW + (size_t)hh * WW + ww;
        qpat[c][i][j] = noisy[idx];
        dpat[c][i][j] = deno[idx];
    }
    __syncthreads();

    // --- one thread per offset: L2 distance noisy-query vs noisy-candidate (from LDS) ---
    if (tid < NOFF) {
        const int dti = tid / (WS * WS);
        const int rr  = tid % (WS * WS);
        const int dh  = rr / WS - WS / 2;
        const int dw  = rr % WS - WS / 2;
        const int hcu = hcen[dti] + dh;            // unclamped candidate center
        const int wcu = wcen[dti] + dw;
        const int hc  = min(max(hcu, 0), HH - 1);
        const int wc  = min(max(wcu, 0), WW - 1);
        const int h0  = h0s[dti], w0 = w0s[dti];
        float acc = 0.f;
        if (hcu >= 0 && hcu + PS <= HH && wcu >= 0 && wcu + PS <= WW) {
            // fast path: no clamps, contiguous rows in the tile
            const float* p = &tile[dti][0][hc - h0][wc - w0];
            #pragma unroll
            for (int c = 0; c < CC; ++c) {
                const float* pc = p + c * (TILE * TILE);
                #pragma unroll
                for (int i = 0; i < PS; ++i) {
                    const float* row = pc + i * TILE;
                    #pragma unroll
                    for (int j = 0; j < PS; ++j) {
                        const float dlt = qpat[c][i][j] - row[j];
                        acc += dlt * dlt;
                    }
                }
            }
        } else {
            // edge path: per-element clamps mapped into the tile
            #pragma unroll
            for (int c = 0; c < CC; ++c) {
                #pragma unroll
                for (int i = 0; i < PS; ++i) {
                    const int hh = min(hc + i, HH - 1) - h0;
                    #pragma unroll
                    for (int j = 0; j < PS; ++j) {
                        const int ww = min(wc + j, WW - 1) - w0;
                        const float dlt = qpat[c][i][j] - tile[dti][c][hh][ww];
                        acc += dlt * dlt;
                    }
                }
            }
        }
        dists[tid] = acc;
    }
    __syncthreads();
    if (tid == 0) dists[SELF_IDX] = -INFINITY;  // anchor self to slot 0
    __syncthreads();

    // --- wave-0 iterative argmin (k_eff picks, ties -> lowest index) ---
    if (tid < 64) {
        for (int k = 0; k < k_eff; ++k) {
            float bv = INFINITY;
            int   bi = NOFF;
            for (int n = tid; n < NOFF; n += 64) {
                const float v = dists[n];      // ascending scan: strict < keeps lowest idx
                if (v < bv) { bv = v; bi = n; }
            }
            for (int off = 32; off > 0; off >>= 1) {
                const float ov = __shfl_down(bv, off);
                const int   oi = __shfl_down(bi, off);
                if (ov < bv || (ov == bv && oi < bi)) { bv = ov; bi = oi; }
            }
            bi = __shfl(bi, 0);
            if (tid == 0) sel[k] = bi;
            dists[bi] = INFINITY;              // all lanes write same value: benign
        }
    }
    __syncthreads();

    // --- refine: deno-query vs noisy at selected positions (slots 1..k_eff-1), from LDS ---
    float part = 0.f;
    const int nref = (k_eff - 1) * PS * PS;
    for (int u = tid; u < nref; u += 256) {
        const int k  = u / (PS * PS) + 1;
        const int ij = u % (PS * PS);
        const int i  = ij / PS, j = ij % PS;
        const int n  = sel[k];
        const int dti = n / (WS * WS);
        const int rr  = n % (WS * WS);
        const int dh  = rr / WS - WS / 2;
        const int dw  = rr % WS - WS / 2;
        const int hc  = min(max(hcen[dti] + dh, 0), HH - 1);
        const int wc  = min(max(wcen[dti] + dw, 0), WW - 1);
        const int hh  = min(hc + i, HH - 1) - h0s[dti];
        const int ww  = min(wc + j, WW - 1) - w0s[dti];
        #pragma unroll
        for (int c = 0; c < CC; ++c) {
            const float dlt = dpat[c][i][j] - tile[dti][c][hh][ww];
            part += dlt * dlt;
        }
    }

    red[tid] = part;
    __syncthreads();
    for (int s = 128; s > 0; s >>= 1) {
        if (tid < s) red[tid] += red[tid + s];
        __syncthreads();
    }
    if (tid == 0) partial[q] = red[0];
}

__global__ __launch_bounds__(1024) void dnls_reduce_kernel(
    const float* __restrict__ partial, int n,
    const int* __restrict__ ep_ptr, float* __restrict__ out)
{
    const int tid = threadIdx.x;
    double acc = 0.0;
    for (int i = tid; i < n; i += 1024) acc += (double)partial[i];
    __shared__ double red[1024];
    red[tid] = acc;
    __syncthreads();
    for (int s = 512; s > 0; s >>= 1) {
        if (tid < s) red[tid] += red[tid + s];
        __syncthreads();
    }
    if (tid == 0) {
        const int k_eff = k_eff_from_epoch(ep_ptr[0]);
        out[0] = (float)(red[0] / ((double)n * (double)(k_eff - 1)));
    }
}

extern "C" void kernel_launch(void* const* d_in, const int* in_sizes, int n_in,
                              void* d_out, int out_size, void* d_ws, size_t ws_size,
                              hipStream_t stream) {
    const float* noisy = (const float*)d_in[0];
    const float* deno  = (const float*)d_in[1];
    const float* fflow = (const float*)d_in[2];
    const float* bflow = (const float*)d_in[3];
    const int*   ep    = (const int*)d_in[4];
    float* partial = (float*)d_ws;            // BB*QQ floats = 80 KB
    float* out = (float*)d_out;

    dnls_query_kernel<<<BB * QQ, 256, 0, stream>>>(noisy, deno, fflow, bflow, ep, partial);
    dnls_reduce_kernel<<<1, 1024, 0, stream>>>(partial, BB * QQ, ep, out);
}